// Round 1
// baseline (515.972 us; speedup 1.0000x reference)
//
#include <hip/hip_runtime.h>

// 3-layer GCN (PyG GCNConv semantics): deg/norm build -> CSR by dst ->
// per layer: GEMM (N x 128 @ 128 x 128) then CSR aggregation + bias (+relu),
// final 128->16 linear. All fp32.

#define FD 128
#define NCLS 16

__global__ __launch_bounds__(256) void k_init_deg(int* __restrict__ degi, int n) {
  int i = blockIdx.x * 256 + threadIdx.x;
  if (i < n) degi[i] = 1;  // self-loop
}

__global__ __launch_bounds__(256) void k_count(const int* __restrict__ dst,
                                               int* __restrict__ degi, int e) {
  int i = blockIdx.x * 256 + threadIdx.x;
  if (i < e) atomicAdd(&degi[dst[i]], 1);
}

__global__ __launch_bounds__(256) void k_dis(const int* __restrict__ degi,
                                             float* __restrict__ dis, int n) {
  int i = blockIdx.x * 256 + threadIdx.x;
  if (i < n) dis[i] = rsqrtf((float)degi[i]);
}

// Phase A: per-1024-chunk exclusive scan of (deg-1) = in-edge count
__global__ __launch_bounds__(1024) void k_scanA(const int* __restrict__ degi,
                                                int* __restrict__ ptr,
                                                int* __restrict__ bsum, int n) {
  __shared__ int buf[1024];
  int tid = threadIdx.x;
  int i = blockIdx.x * 1024 + tid;
  int v = (i < n) ? (degi[i] - 1) : 0;
  buf[tid] = v;
  __syncthreads();
  for (int off = 1; off < 1024; off <<= 1) {
    int t = (tid >= off) ? buf[tid - off] : 0;
    __syncthreads();
    buf[tid] += t;
    __syncthreads();
  }
  if (i < n) ptr[i] = buf[tid] - v;  // local exclusive
  if (tid == 1023) bsum[blockIdx.x] = buf[1023];
}

// Phase B: tiny serial scan of ~49 block sums
__global__ void k_scanB(int* __restrict__ bsum, int nb) {
  if (threadIdx.x == 0 && blockIdx.x == 0) {
    int run = 0;
    for (int b = 0; b < nb; ++b) { int t = bsum[b]; bsum[b] = run; run += t; }
  }
}

// Phase C: add chunk offsets, init fill cursors, write ptr[n]
__global__ __launch_bounds__(256) void k_scanC(int* __restrict__ ptr,
                                               int* __restrict__ cur,
                                               const int* __restrict__ bsum,
                                               int n, int e) {
  int i = blockIdx.x * 256 + threadIdx.x;
  if (i < n) {
    int p = ptr[i] + bsum[i >> 10];
    ptr[i] = p;
    cur[i] = p;
  }
  if (i == 0) ptr[n] = e;
}

__global__ __launch_bounds__(256) void k_fill(const int* __restrict__ src,
                                              const int* __restrict__ dst,
                                              int* __restrict__ cur,
                                              const float* __restrict__ dis,
                                              int* __restrict__ srcs,
                                              float* __restrict__ nrm, int e) {
  int i = blockIdx.x * 256 + threadIdx.x;
  if (i < e) {
    int s = src[i], d = dst[i];
    int p = atomicAdd(&cur[d], 1);
    srcs[p] = s;
    nrm[p] = dis[s] * dis[d];
  }
}

// out[rbase..rbase+15][:] = in rows @ W (128x128). blockDim=128, 16 rows/block.
__global__ __launch_bounds__(128) void k_gemm128(const float* __restrict__ in,
                                                 const float* __restrict__ W,
                                                 float* __restrict__ out) {
  __shared__ float lin[16][FD];
  int tid = threadIdx.x;
  int rbase = blockIdx.x * 16;
#pragma unroll
  for (int r = 0; r < 16; ++r)
    lin[r][tid] = in[(rbase + r) * FD + tid];
  __syncthreads();
  float acc[16];
#pragma unroll
  for (int r = 0; r < 16; ++r) acc[r] = 0.f;
  for (int k = 0; k < FD; k += 4) {
    float w0 = W[(k + 0) * FD + tid];
    float w1 = W[(k + 1) * FD + tid];
    float w2 = W[(k + 2) * FD + tid];
    float w3 = W[(k + 3) * FD + tid];
#pragma unroll
    for (int r = 0; r < 16; ++r) {
      float4 l = *reinterpret_cast<const float4*>(&lin[r][k]);
      acc[r] = fmaf(l.x, w0, acc[r]);
      acc[r] = fmaf(l.y, w1, acc[r]);
      acc[r] = fmaf(l.z, w2, acc[r]);
      acc[r] = fmaf(l.w, w3, acc[r]);
    }
  }
#pragma unroll
  for (int r = 0; r < 16; ++r)
    out[(rbase + r) * FD + tid] = acc[r];
}

// One block (128 threads) per node: self-loop + CSR in-edge accumulation.
__global__ __launch_bounds__(128) void k_agg(const float* __restrict__ t,
                                             const int* __restrict__ ptr,
                                             const int* __restrict__ srcs,
                                             const float* __restrict__ nrm,
                                             const float* __restrict__ dis,
                                             const float* __restrict__ bias,
                                             float* __restrict__ out, int relu) {
  int node = blockIdx.x;
  int f = threadIdx.x;
  float d = dis[node];
  float acc = t[node * FD + f] * (d * d);
  int e0 = ptr[node], e1 = ptr[node + 1];
  for (int e = e0; e < e1; ++e) {
    int s = srcs[e];
    float w = nrm[e];
    acc = fmaf(t[s * FD + f], w, acc);
  }
  acc += bias[f];
  if (relu) acc = fmaxf(acc, 0.f);
  out[node * FD + f] = acc;
}

// out[N x 16] = h @ Wlin + blin. blockDim=256: 16 rows x 16 cols per block.
__global__ __launch_bounds__(256) void k_linear16(const float* __restrict__ h,
                                                  const float* __restrict__ Wl,
                                                  const float* __restrict__ bl,
                                                  float* __restrict__ out) {
  __shared__ float hl[16][FD + 1];  // +1 pad: avoid 4-way bank conflict on hl[r][k]
  __shared__ float wl[FD][NCLS];
  int tid = threadIdx.x;
  int rbase = blockIdx.x * 16;
  for (int i = tid; i < 16 * FD; i += 256) {
    int r = i >> 7, k = i & 127;
    hl[r][k] = h[(rbase + r) * FD + k];
  }
  for (int i = tid; i < FD * NCLS; i += 256)
    wl[i >> 4][i & 15] = Wl[i];
  __syncthreads();
  int r = tid >> 4, c = tid & 15;
  float acc = bl[c];
#pragma unroll
  for (int k = 0; k < FD; ++k)
    acc = fmaf(hl[r][k], wl[k][c], acc);
  out[(rbase + r) * NCLS + c] = acc;
}

extern "C" void kernel_launch(void* const* d_in, const int* in_sizes, int n_in,
                              void* d_out, int out_size, void* d_ws, size_t ws_size,
                              hipStream_t stream) {
  const float* x  = (const float*)d_in[0];
  const int*   ei = (const int*)d_in[1];
  const float* W1 = (const float*)d_in[2];
  const float* b1 = (const float*)d_in[3];
  const float* W2 = (const float*)d_in[4];
  const float* b2 = (const float*)d_in[5];
  const float* W3 = (const float*)d_in[6];
  const float* b3 = (const float*)d_in[7];
  const float* Wl = (const float*)d_in[8];
  const float* bl = (const float*)d_in[9];
  float* out = (float*)d_out;

  const int n = in_sizes[0] / FD;      // 50000
  const int e = in_sizes[1] / 2;       // 600000
  const int* src = ei;                 // edge_index[0]
  const int* dst = ei + e;             // edge_index[1]

  // workspace carve (all 4-byte types; total ~57 MB)
  float* bufT = (float*)d_ws;                  // n*FD
  float* bufH = bufT + (size_t)n * FD;         // n*FD
  int*   degi = (int*)(bufH + (size_t)n * FD); // n
  float* dis  = (float*)(degi + n);            // n
  int*   ptr  = (int*)(dis + n);               // n+1
  int*   cur  = ptr + n + 1;                   // n
  int*   srcs = cur + n;                       // e
  float* nrm  = (float*)(srcs + e);            // e
  int*   bsum = (int*)(nrm + e);               // <=64

  const int gn = (n + 255) / 256;
  const int ge = (e + 255) / 256;
  const int nb = (n + 1023) / 1024;

  k_init_deg<<<gn, 256, 0, stream>>>(degi, n);
  k_count<<<ge, 256, 0, stream>>>(dst, degi, e);
  k_dis<<<gn, 256, 0, stream>>>(degi, dis, n);
  k_scanA<<<nb, 1024, 0, stream>>>(degi, ptr, bsum, n);
  k_scanB<<<1, 64, 0, stream>>>(bsum, nb);
  k_scanC<<<gn, 256, 0, stream>>>(ptr, cur, bsum, n, e);
  k_fill<<<ge, 256, 0, stream>>>(src, dst, cur, dis, srcs, nrm, e);

  const int gg = n / 16;  // 3125 (n divisible by 16)

  k_gemm128<<<gg, 128, 0, stream>>>(x, W1, bufT);
  k_agg<<<n, 128, 0, stream>>>(bufT, ptr, srcs, nrm, dis, b1, bufH, 1);
  k_gemm128<<<gg, 128, 0, stream>>>(bufH, W2, bufT);
  k_agg<<<n, 128, 0, stream>>>(bufT, ptr, srcs, nrm, dis, b2, bufH, 1);
  k_gemm128<<<gg, 128, 0, stream>>>(bufH, W3, bufT);
  k_agg<<<n, 128, 0, stream>>>(bufT, ptr, srcs, nrm, dis, b3, bufH, 0);
  k_linear16<<<gg, 256, 0, stream>>>(bufH, Wl, bl, out);
}

// Round 2
// 422.981 us; speedup vs baseline: 1.2198x; 1.2198x over previous
//
#include <hip/hip_runtime.h>

// 3-layer GCN (PyG GCNConv semantics): deg/norm build -> CSR by dst ->
// per layer: GEMM (N x 128 @ 128 x 128) then CSR aggregation + bias (+relu),
// final 128->16 linear fused into the last aggregation. All fp32.
//
// R2: aggregation batches edges 8-at-a-time (8 independent gathers in flight
// per thread instead of a serial dependent-load chain), (src,norm) packed as
// int2 so the first chain link is one 8B broadcast load.

#define FD 128
#define NCLS 16

__global__ __launch_bounds__(256) void k_init_deg(int* __restrict__ degi, int n) {
  int i = blockIdx.x * 256 + threadIdx.x;
  if (i < n) degi[i] = 1;  // self-loop
}

__global__ __launch_bounds__(256) void k_count(const int* __restrict__ dst,
                                               int* __restrict__ degi, int e) {
  int i = blockIdx.x * 256 + threadIdx.x;
  if (i < e) atomicAdd(&degi[dst[i]], 1);
}

__global__ __launch_bounds__(256) void k_dis(const int* __restrict__ degi,
                                             float* __restrict__ dis, int n) {
  int i = blockIdx.x * 256 + threadIdx.x;
  if (i < n) dis[i] = rsqrtf((float)degi[i]);
}

// Phase A: per-1024-chunk exclusive scan of (deg-1) = in-edge count
__global__ __launch_bounds__(1024) void k_scanA(const int* __restrict__ degi,
                                                int* __restrict__ ptr,
                                                int* __restrict__ bsum, int n) {
  __shared__ int buf[1024];
  int tid = threadIdx.x;
  int i = blockIdx.x * 1024 + tid;
  int v = (i < n) ? (degi[i] - 1) : 0;
  buf[tid] = v;
  __syncthreads();
  for (int off = 1; off < 1024; off <<= 1) {
    int t = (tid >= off) ? buf[tid - off] : 0;
    __syncthreads();
    buf[tid] += t;
    __syncthreads();
  }
  if (i < n) ptr[i] = buf[tid] - v;  // local exclusive
  if (tid == 1023) bsum[blockIdx.x] = buf[1023];
}

// Phase B: tiny serial scan of ~49 block sums
__global__ void k_scanB(int* __restrict__ bsum, int nb) {
  if (threadIdx.x == 0 && blockIdx.x == 0) {
    int run = 0;
    for (int b = 0; b < nb; ++b) { int t = bsum[b]; bsum[b] = run; run += t; }
  }
}

// Phase C: add chunk offsets, init fill cursors, write ptr[n]
__global__ __launch_bounds__(256) void k_scanC(int* __restrict__ ptr,
                                               int* __restrict__ cur,
                                               const int* __restrict__ bsum,
                                               int n, int e) {
  int i = blockIdx.x * 256 + threadIdx.x;
  if (i < n) {
    int p = ptr[i] + bsum[i >> 10];
    ptr[i] = p;
    cur[i] = p;
  }
  if (i == 0) ptr[n] = e;
}

__global__ __launch_bounds__(256) void k_fill(const int* __restrict__ src,
                                              const int* __restrict__ dst,
                                              int* __restrict__ cur,
                                              const float* __restrict__ dis,
                                              int2* __restrict__ sn, int e) {
  int i = blockIdx.x * 256 + threadIdx.x;
  if (i < e) {
    int s = src[i], d = dst[i];
    int p = atomicAdd(&cur[d], 1);
    sn[p] = make_int2(s, __float_as_int(dis[s] * dis[d]));
  }
}

// out[rbase..rbase+15][:] = in rows @ W (128x128). blockDim=128, 16 rows/block.
__global__ __launch_bounds__(128) void k_gemm128(const float* __restrict__ in,
                                                 const float* __restrict__ W,
                                                 float* __restrict__ out) {
  __shared__ float lin[16][FD];
  int tid = threadIdx.x;
  int rbase = blockIdx.x * 16;
#pragma unroll
  for (int r = 0; r < 16; ++r)
    lin[r][tid] = in[(rbase + r) * FD + tid];
  __syncthreads();
  float acc[16];
#pragma unroll
  for (int r = 0; r < 16; ++r) acc[r] = 0.f;
  for (int k = 0; k < FD; k += 4) {
    float w0 = W[(k + 0) * FD + tid];
    float w1 = W[(k + 1) * FD + tid];
    float w2 = W[(k + 2) * FD + tid];
    float w3 = W[(k + 3) * FD + tid];
#pragma unroll
    for (int r = 0; r < 16; ++r) {
      float4 l = *reinterpret_cast<const float4*>(&lin[r][k]);
      acc[r] = fmaf(l.x, w0, acc[r]);
      acc[r] = fmaf(l.y, w1, acc[r]);
      acc[r] = fmaf(l.z, w2, acc[r]);
      acc[r] = fmaf(l.w, w3, acc[r]);
    }
  }
#pragma unroll
  for (int r = 0; r < 16; ++r)
    out[(rbase + r) * FD + tid] = acc[r];
}

// Batched CSR aggregation: 8 independent gathers in flight per thread.
// Short batches padded with (node, w=0); self row is cache-hot so the
// padded gathers are near-free.
__device__ __forceinline__ float agg_acc(const float* __restrict__ t,
                                         const int* __restrict__ ptr,
                                         const int2* __restrict__ sn,
                                         const float* __restrict__ dis,
                                         int node, int f) {
  float d = dis[node];
  float acc = t[node * FD + f] * (d * d);
  int e0 = ptr[node], e1 = ptr[node + 1];
  for (int e = e0; e < e1; e += 8) {
    int s[8];
    float w[8];
#pragma unroll
    for (int j = 0; j < 8; ++j) {
      if (e + j < e1) {
        int2 p = sn[e + j];
        s[j] = p.x;
        w[j] = __int_as_float(p.y);
      } else {
        s[j] = node;
        w[j] = 0.f;
      }
    }
    float v[8];
#pragma unroll
    for (int j = 0; j < 8; ++j) v[j] = t[s[j] * FD + f];
#pragma unroll
    for (int j = 0; j < 8; ++j) acc = fmaf(v[j], w[j], acc);
  }
  return acc;
}

// One block (128 threads) per node: aggregation + bias (+relu).
__global__ __launch_bounds__(128) void k_agg(const float* __restrict__ t,
                                             const int* __restrict__ ptr,
                                             const int2* __restrict__ sn,
                                             const float* __restrict__ dis,
                                             const float* __restrict__ bias,
                                             float* __restrict__ out, int relu) {
  int node = blockIdx.x;
  int f = threadIdx.x;
  float acc = agg_acc(t, ptr, sn, dis, node, f) + bias[f];
  if (relu) acc = fmaxf(acc, 0.f);
  out[node * FD + f] = acc;
}

// Last layer: aggregation + b3, then fused h @ Wlin + blin -> out[node][16].
__global__ __launch_bounds__(128) void k_agg_lin(const float* __restrict__ t,
                                                 const int* __restrict__ ptr,
                                                 const int2* __restrict__ sn,
                                                 const float* __restrict__ dis,
                                                 const float* __restrict__ b3,
                                                 const float* __restrict__ Wl,
                                                 const float* __restrict__ bl,
                                                 float* __restrict__ out) {
  __shared__ float hl[FD];
  __shared__ float part[8][NCLS];
  int node = blockIdx.x;
  int f = threadIdx.x;
  hl[f] = agg_acc(t, ptr, sn, dis, node, f) + b3[f];
  __syncthreads();
  int c = f & 15, p = f >> 4;  // 8 partials x 16 cols
  float s = 0.f;
#pragma unroll
  for (int k = 0; k < 16; ++k)
    s = fmaf(hl[p * 16 + k], Wl[(p * 16 + k) * NCLS + c], s);
  part[p][c] = s;
  __syncthreads();
  if (f < NCLS) {
    float r = bl[f];
#pragma unroll
    for (int q = 0; q < 8; ++q) r += part[q][f];
    out[node * NCLS + f] = r;
  }
}

extern "C" void kernel_launch(void* const* d_in, const int* in_sizes, int n_in,
                              void* d_out, int out_size, void* d_ws, size_t ws_size,
                              hipStream_t stream) {
  const float* x  = (const float*)d_in[0];
  const int*   ei = (const int*)d_in[1];
  const float* W1 = (const float*)d_in[2];
  const float* b1 = (const float*)d_in[3];
  const float* W2 = (const float*)d_in[4];
  const float* b2 = (const float*)d_in[5];
  const float* W3 = (const float*)d_in[6];
  const float* b3 = (const float*)d_in[7];
  const float* Wl = (const float*)d_in[8];
  const float* bl = (const float*)d_in[9];
  float* out = (float*)d_out;

  const int n = in_sizes[0] / FD;      // 50000
  const int e = in_sizes[1] / 2;       // 600000
  const int* src = ei;                 // edge_index[0]
  const int* dst = ei + e;             // edge_index[1]

  // workspace carve (all 4/8-byte types)
  float* bufT = (float*)d_ws;                  // n*FD
  float* bufH = bufT + (size_t)n * FD;         // n*FD
  int*   degi = (int*)(bufH + (size_t)n * FD); // n
  float* dis  = (float*)(degi + n);            // n
  int*   ptr  = (int*)(dis + n);               // n+1
  int*   cur  = ptr + n + 1;                   // n
  int*   bsum = cur + n;                       // <=64
  int2*  sn   = (int2*)(((uintptr_t)(bsum + 64) + 15) & ~(uintptr_t)15);  // e pairs

  const int gn = (n + 255) / 256;
  const int ge = (e + 255) / 256;
  const int nb = (n + 1023) / 1024;

  k_init_deg<<<gn, 256, 0, stream>>>(degi, n);
  k_count<<<ge, 256, 0, stream>>>(dst, degi, e);
  k_dis<<<gn, 256, 0, stream>>>(degi, dis, n);
  k_scanA<<<nb, 1024, 0, stream>>>(degi, ptr, bsum, n);
  k_scanB<<<1, 64, 0, stream>>>(bsum, nb);
  k_scanC<<<gn, 256, 0, stream>>>(ptr, cur, bsum, n, e);
  k_fill<<<ge, 256, 0, stream>>>(src, dst, cur, dis, sn, e);

  const int gg = n / 16;  // 3125 (n divisible by 16)

  k_gemm128<<<gg, 128, 0, stream>>>(x, W1, bufT);
  k_agg<<<n, 128, 0, stream>>>(bufT, ptr, sn, dis, b1, bufH, 1);
  k_gemm128<<<gg, 128, 0, stream>>>(bufH, W2, bufT);
  k_agg<<<n, 128, 0, stream>>>(bufT, ptr, sn, dis, b2, bufH, 1);
  k_gemm128<<<gg, 128, 0, stream>>>(bufH, W3, bufT);
  k_agg_lin<<<n, 128, 0, stream>>>(bufT, ptr, sn, dis, b3, Wl, bl, out);
}